// Round 5
// baseline (419.722 us; speedup 1.0000x reference)
//
#include <hip/hip_runtime.h>
#include <cstdint>
#include <cstddef>

#define NB    2
#define N1    4096
#define N2    16384
#define CF    64
#define KNN   8
#define SPLIT 4
#define NS    (N1 / SPLIT)   // 1024 candidates per split

// ---------------------------------------------------------------------------
// Scalarized stable top-8 insert (used in merge kernel): strict <, descending
// update order reading pre-update values -> lower index wins ties (= top_k).
// ---------------------------------------------------------------------------
#define TKDECL(P) \
    float P##d0=INFINITY,P##d1=INFINITY,P##d2=INFINITY,P##d3=INFINITY, \
          P##d4=INFINITY,P##d5=INFINITY,P##d6=INFINITY,P##d7=INFINITY; \
    int   P##i0=0,P##i1=0,P##i2=0,P##i3=0,P##i4=0,P##i5=0,P##i6=0,P##i7=0

#define TKINS(P, dv, ix) do { \
    const bool c0_ = (dv) < P##d0, c1_ = (dv) < P##d1, c2_ = (dv) < P##d2, c3_ = (dv) < P##d3; \
    const bool c4_ = (dv) < P##d4, c5_ = (dv) < P##d5, c6_ = (dv) < P##d6, c7_ = (dv) < P##d7; \
    P##d7 = c6_ ? P##d6 : (c7_ ? (dv) : P##d7);  P##i7 = c6_ ? P##i6 : (c7_ ? (ix) : P##i7); \
    P##d6 = c5_ ? P##d5 : (c6_ ? (dv) : P##d6);  P##i6 = c5_ ? P##i5 : (c6_ ? (ix) : P##i6); \
    P##d5 = c4_ ? P##d4 : (c5_ ? (dv) : P##d5);  P##i5 = c4_ ? P##i4 : (c5_ ? (ix) : P##i5); \
    P##d4 = c3_ ? P##d3 : (c4_ ? (dv) : P##d4);  P##i4 = c3_ ? P##i3 : (c4_ ? (ix) : P##i4); \
    P##d3 = c2_ ? P##d2 : (c3_ ? (dv) : P##d3);  P##i3 = c2_ ? P##i2 : (c3_ ? (ix) : P##i3); \
    P##d2 = c1_ ? P##d1 : (c2_ ? (dv) : P##d2);  P##i2 = c1_ ? P##i1 : (c2_ ? (ix) : P##i2); \
    P##d1 = c0_ ? P##d0 : (c1_ ? (dv) : P##d1);  P##i1 = c0_ ? P##i0 : (c1_ ? (ix) : P##i1); \
    P##d0 = c0_ ? (dv) : P##d0;                  P##i0 = c0_ ? (ix) : P##i0; \
} while (0)

// ---------------------------------------------------------------------------
// kernel 0: transpose feat1 [B,C,N1] -> feat1T [B,N1,C]; pack xyz1/flow float4
// ---------------------------------------------------------------------------
__global__ __launch_bounds__(256, 2) void k_pack(
    const float* __restrict__ xyz1, const float* __restrict__ feat1,
    const float* __restrict__ flow,
    float* __restrict__ feat1T, float4* __restrict__ aux4,
    float4* __restrict__ flow4)
{
    __shared__ float tile[64][65];
    const int b  = blockIdx.y;
    const int n0 = blockIdx.x * 64;
    const int tid = threadIdx.x;
    const int nl = tid & 63, cq = tid >> 6;

#pragma unroll
    for (int r = 0; r < 16; ++r) {
        const int c = r * 4 + cq;
        tile[c][nl] = feat1[((size_t)(b * CF + c)) * N1 + n0 + nl];
    }
    __syncthreads();
#pragma unroll
    for (int r = 0; r < 16; ++r) {
        const int nn = r * 4 + cq;
        feat1T[((size_t)(b * N1 + n0 + nn)) * CF + nl] = tile[nl][nn];
    }
    if (tid < 64) {
        const int n = n0 + tid;
        const float x = xyz1[(b * 3 + 0) * N1 + n];
        const float y = xyz1[(b * 3 + 1) * N1 + n];
        const float z = xyz1[(b * 3 + 2) * N1 + n];
        aux4[b * N1 + n] = make_float4(x, y, z, 0.f);
        const float fx = flow[(b * 3 + 0) * N1 + n];
        const float fy = flow[(b * 3 + 1) * N1 + n];
        const float fz = flow[(b * 3 + 2) * N1 + n];
        flow4[b * N1 + n] = make_float4(fx, fy, fz, 0.f);
    }
}

// ---------------------------------------------------------------------------
// kernel 1: partial KNN, QPT=1, SPLIT=4 (scan 1024).
// Distance update: compare-free min/max sorting network (pure VOP2, no SGPR
// condition pressure). Index update: gated behind (d < d7) — idle ~15% of
// iterations at scan length 1024 — using compares on the PRE-update list.
// Equal semantics to stable TKINS: d==d7 skips (strict <); duplicates keep
// lower index. Distance replicates reference fp32 rounding exactly:
// d = (q2 + t2) - (qt + qt), qt = ((qx*tx + qy*ty) + qz*tz), all _rn.
// ---------------------------------------------------------------------------
__global__ __launch_bounds__(256, 2) void k_knn3(
    const float* __restrict__ xyz1, const float* __restrict__ xyz2,
    float* __restrict__ partd, int* __restrict__ parti)
{
    __shared__ float4 pts[NS];  // {x, y, z, t2} — 16 KiB
    const int sp  = blockIdx.y;
    const int tid = threadIdx.x;
    const int q   = blockIdx.x * 256 + tid;
    const int b   = q >> 14;     // uniform per block

    for (int t = tid; t < NS; t += 256) {
        const int jg = sp * NS + t;
        const float x = xyz1[(b * 3 + 0) * N1 + jg];
        const float y = xyz1[(b * 3 + 1) * N1 + jg];
        const float z = xyz1[(b * 3 + 2) * N1 + jg];
        const float t2 = __fadd_rn(__fadd_rn(__fmul_rn(x, x), __fmul_rn(y, y)),
                                   __fmul_rn(z, z));
        pts[t] = make_float4(x, y, z, t2);
    }
    __syncthreads();

    const int n = q & (N2 - 1);
    const float qx = xyz2[(b * 3 + 0) * N2 + n];
    const float qy = xyz2[(b * 3 + 1) * N2 + n];
    const float qz = xyz2[(b * 3 + 2) * N2 + n];
    const float q2 = __fadd_rn(__fadd_rn(__fmul_rn(qx, qx), __fmul_rn(qy, qy)),
                               __fmul_rn(qz, qz));

    float d0=INFINITY,d1=INFINITY,d2=INFINITY,d3=INFINITY,
          d4=INFINITY,d5=INFINITY,d6=INFINITY,d7=INFINITY;
    int   i0=0,i1=0,i2=0,i3=0,i4=0,i5=0,i6=0,i7=0;

#pragma unroll 4
    for (int j = 0; j < NS; ++j) {
        const float4 p = pts[j];
        const int idx = sp * NS + j;
        const float qt = __fadd_rn(
            __fadd_rn(__fmul_rn(qx, p.x), __fmul_rn(qy, p.y)),
            __fmul_rn(qz, p.z));
        const float d = __fsub_rn(__fadd_rn(q2, p.w), __fadd_rn(qt, qt));

        // compare-free sorted-list distance update (reads old d0..d7)
        const float m0 = fminf(d, d0);
        const float m1 = fminf(fmaxf(d, d0), d1);
        const float m2 = fminf(fmaxf(d, d1), d2);
        const float m3 = fminf(fmaxf(d, d2), d3);
        const float m4 = fminf(fmaxf(d, d3), d4);
        const float m5 = fminf(fmaxf(d, d4), d5);
        const float m6 = fminf(fmaxf(d, d5), d6);
        const float m7 = fminf(fmaxf(d, d6), d7);

        if (d < d7) {   // index update only when membership changes
            const bool c0 = d < d0, c1 = d < d1, c2 = d < d2, c3 = d < d3;
            const bool c4 = d < d4, c5 = d < d5, c6 = d < d6;
            i7 = c6 ? i6 : idx;                    // c7 true inside gate
            i6 = c5 ? i5 : (c6 ? idx : i6);
            i5 = c4 ? i4 : (c5 ? idx : i5);
            i4 = c3 ? i3 : (c4 ? idx : i4);
            i3 = c2 ? i2 : (c3 ? idx : i3);
            i2 = c1 ? i1 : (c2 ? idx : i2);
            i1 = c0 ? i0 : (c1 ? idx : i1);
            i0 = c0 ? idx : i0;
        }
        d0=m0; d1=m1; d2=m2; d3=m3; d4=m4; d5=m5; d6=m6; d7=m7;
    }

    float* pd = partd + ((size_t)q * SPLIT + sp) * KNN;
    int*   pi = parti + ((size_t)q * SPLIT + sp) * KNN;
    pd[0]=d0; pd[1]=d1; pd[2]=d2; pd[3]=d3; pd[4]=d4; pd[5]=d5; pd[6]=d6; pd[7]=d7;
    pi[0]=i0; pi[1]=i1; pi[2]=i2; pi[3]=i3; pi[4]=i4; pi[5]=i5; pi[6]=i6; pi[7]=i7;
}

// ---------------------------------------------------------------------------
// kernel 2: merge SPLIT partial top-8 lists (ascending split order -> stable)
// ---------------------------------------------------------------------------
__global__ __launch_bounds__(256, 2) void k_merge2(
    const float* __restrict__ partd, const int* __restrict__ parti,
    int* __restrict__ knn_idx)
{
    const int q = blockIdx.x * 256 + threadIdx.x;
    const float* pd = partd + (size_t)q * SPLIT * KNN;
    const int*   pi = parti + (size_t)q * SPLIT * KNN;

    TKDECL(M);
#pragma unroll
    for (int t = 0; t < SPLIT * KNN; ++t) {
        const float d = pd[t];
        const int   i = pi[t];
        TKINS(M, d, i);
    }
    int* ko = knn_idx + (size_t)q * KNN;
    ko[0]=Mi0; ko[1]=Mi1; ko[2]=Mi2; ko[3]=Mi3; ko[4]=Mi4; ko[5]=Mi5; ko[6]=Mi6; ko[7]=Mi7;
}

// ---------------------------------------------------------------------------
// kernel 3: gather + MLP + softmax + weighted flow sum — unchanged from R4
// (needs counters before touching; fully scalarized, W1 row in registers)
// ---------------------------------------------------------------------------
#define ACC4(h, wv, iv) \
    h = fmaf((wv).x, (iv).x, h); h = fmaf((wv).y, (iv).y, h); \
    h = fmaf((wv).z, (iv).z, h); h = fmaf((wv).w, (iv).w, h)

#define DOT17(h, ivr) do { \
    ACC4(h, w0,  (ivr)[0]);  ACC4(h, w1,  (ivr)[1]);  ACC4(h, w2,  (ivr)[2]); \
    ACC4(h, w3,  (ivr)[3]);  ACC4(h, w4,  (ivr)[4]);  ACC4(h, w5,  (ivr)[5]); \
    ACC4(h, w6,  (ivr)[6]);  ACC4(h, w7,  (ivr)[7]);  ACC4(h, w8,  (ivr)[8]); \
    ACC4(h, w9,  (ivr)[9]);  ACC4(h, w10, (ivr)[10]); ACC4(h, w11, (ivr)[11]); \
    ACC4(h, w12, (ivr)[12]); ACC4(h, w13, (ivr)[13]); ACC4(h, w14, (ivr)[14]); \
    ACC4(h, w15, (ivr)[15]); ACC4(h, w16, (ivr)[16]); \
} while (0)

#define BFLY(p) \
    p += __shfl_xor(p, 32, 64); p += __shfl_xor(p, 16, 64); \
    p += __shfl_xor(p,  8, 64); p += __shfl_xor(p,  4, 64); \
    p += __shfl_xor(p,  2, 64); p += __shfl_xor(p,  1, 64)

#define L2RED(hk, a0, a1, a2) do { \
    float hv_ = (hk); hv_ = hv_ >= 0.f ? hv_ : 0.1f * hv_; \
    float p0_ = w2a * hv_, p1_ = w2b * hv_, p2_ = w2c * hv_; \
    BFLY(p0_); BFLY(p1_); BFLY(p2_); \
    a0 = p0_ + b20; a1 = p1_ + b21; a2 = p2_ + b22; \
} while (0)

#define SMAX8(sa, sb, sc, sd, se, sf, sg, sh, CH, res) do { \
    const float m_ = fmaxf(fmaxf(fmaxf(sa, sb), fmaxf(sc, sd)), \
                           fmaxf(fmaxf(se, sf), fmaxf(sg, sh))); \
    const float e0_ = __expf(sa - m_), e1_ = __expf(sb - m_); \
    const float e2_ = __expf(sc - m_), e3_ = __expf(sd - m_); \
    const float e4_ = __expf(se - m_), e5_ = __expf(sf - m_); \
    const float e6_ = __expf(sg - m_), e7_ = __expf(sh - m_); \
    const float S_ = ((e0_ + e1_) + (e2_ + e3_)) + ((e4_ + e5_) + (e6_ + e7_)); \
    float acc_ = e0_ * flf[0 * 4 + CH]; \
    acc_ = fmaf(e1_, flf[1 * 4 + CH], acc_); acc_ = fmaf(e2_, flf[2 * 4 + CH], acc_); \
    acc_ = fmaf(e3_, flf[3 * 4 + CH], acc_); acc_ = fmaf(e4_, flf[4 * 4 + CH], acc_); \
    acc_ = fmaf(e5_, flf[5 * 4 + CH], acc_); acc_ = fmaf(e6_, flf[6 * 4 + CH], acc_); \
    acc_ = fmaf(e7_, flf[7 * 4 + CH], acc_); \
    res = acc_ / S_; \
} while (0)

__global__ __launch_bounds__(256, 2) void k_mlp(
    const float* __restrict__ feat1T, const float4* __restrict__ aux4,
    const float4* __restrict__ flow4, const int* __restrict__ knn_idx,
    const float* __restrict__ xyz2,
    const float* __restrict__ W1, const float* __restrict__ b1,
    const float* __restrict__ W2, const float* __restrict__ b2,
    float* __restrict__ out)
{
    constexpr int QPW = 8;
    __shared__ __align__(16) float w1s[64 * 68];
    __shared__ __align__(16) float inbuf[4][8][68];
    __shared__ __align__(16) float4 flbuf[4][8];

    const int tid = threadIdx.x;
    const int wave = tid >> 6, lane = tid & 63;

    for (int t = tid; t < 64 * 67; t += 256) {
        const int o = t / 67, c = t - o * 67;
        w1s[o * 68 + c] = W1[t];
    }
    if (tid < 64) w1s[tid * 68 + 67] = 0.f;

    const float b1v = b1[lane];
    const float w2a = W2[lane], w2b = W2[64 + lane], w2c = W2[128 + lane];
    const float b20 = b2[0], b21 = b2[1], b22 = b2[2];
    __syncthreads();

    const float4* wr = (const float4*)&w1s[lane * 68];
    const float4 w0 = wr[0],  w1 = wr[1],  w2 = wr[2],  w3 = wr[3];
    const float4 w4 = wr[4],  w5 = wr[5],  w6 = wr[6],  w7 = wr[7];
    const float4 w8 = wr[8],  w9 = wr[9],  w10 = wr[10], w11 = wr[11];
    const float4 w12 = wr[12], w13 = wr[13], w14 = wr[14], w15 = wr[15];
    const float4 w16 = wr[16];

    const int k = lane >> 3, p = lane & 7;
    const float* flf = (const float*)&flbuf[wave][0];

    for (int it = 0; it < QPW; ++it) {
        const int q = blockIdx.x * (4 * QPW) + wave * QPW + it;
        const int b = q >> 14, n = q & (N2 - 1);
        __syncthreads();

        const int idk = knn_idx[(size_t)q * KNN + k];
        const float4* frow = (const float4*)(feat1T + ((size_t)(b * N1 + idk)) * CF);
        const float4 g0 = frow[p * 2], g1 = frow[p * 2 + 1];
        float4* drow = (float4*)(&inbuf[wave][k][0]);
        drow[p * 2] = g0; drow[p * 2 + 1] = g1;
        if (p == 0) {
            const float4 axv = aux4[b * N1 + idk];
            inbuf[wave][k][64] = axv.x - xyz2[(b * 3 + 0) * N2 + n];
            inbuf[wave][k][65] = axv.y - xyz2[(b * 3 + 1) * N2 + n];
            inbuf[wave][k][66] = axv.z - xyz2[(b * 3 + 2) * N2 + n];
            inbuf[wave][k][67] = 0.f;
        }
        if (p == 1) flbuf[wave][k] = flow4[b * N1 + idk];
        __syncthreads();

        float h0 = b1v, h1 = b1v, h2 = b1v, h3 = b1v;
        float h4 = b1v, h5 = b1v, h6 = b1v, h7 = b1v;
        DOT17(h0, ((const float4*)&inbuf[wave][0][0]));
        DOT17(h1, ((const float4*)&inbuf[wave][1][0]));
        DOT17(h2, ((const float4*)&inbuf[wave][2][0]));
        DOT17(h3, ((const float4*)&inbuf[wave][3][0]));
        DOT17(h4, ((const float4*)&inbuf[wave][4][0]));
        DOT17(h5, ((const float4*)&inbuf[wave][5][0]));
        DOT17(h6, ((const float4*)&inbuf[wave][6][0]));
        DOT17(h7, ((const float4*)&inbuf[wave][7][0]));

        float s00, s01, s02, s03, s04, s05, s06, s07;
        float s10, s11, s12, s13, s14, s15, s16, s17;
        float s20, s21, s22, s23, s24, s25, s26, s27;
        L2RED(h0, s00, s10, s20);
        L2RED(h1, s01, s11, s21);
        L2RED(h2, s02, s12, s22);
        L2RED(h3, s03, s13, s23);
        L2RED(h4, s04, s14, s24);
        L2RED(h5, s05, s15, s25);
        L2RED(h6, s06, s16, s26);
        L2RED(h7, s07, s17, s27);

        float res0, res1, res2;
        SMAX8(s00, s01, s02, s03, s04, s05, s06, s07, 0, res0);
        SMAX8(s10, s11, s12, s13, s14, s15, s16, s17, 1, res1);
        SMAX8(s20, s21, s22, s23, s24, s25, s26, s27, 2, res2);

        const float resv = lane == 0 ? res0 : (lane == 1 ? res1 : res2);
        if (lane < 3) out[((size_t)(b * 3 + lane)) * N2 + n] = resv;
    }
}

// ---------------------------------------------------------------------------
extern "C" void kernel_launch(void* const* d_in, const int* in_sizes, int n_in,
                              void* d_out, int out_size, void* d_ws, size_t ws_size,
                              hipStream_t stream)
{
    const float* xyz1  = (const float*)d_in[0];
    const float* xyz2  = (const float*)d_in[1];
    const float* feat1 = (const float*)d_in[2];
    const float* flow  = (const float*)d_in[3];
    const float* W1    = (const float*)d_in[4];
    const float* b1    = (const float*)d_in[5];
    const float* W2    = (const float*)d_in[6];
    const float* b2    = (const float*)d_in[7];
    float* out = (float*)d_out;

    char* ws = (char*)d_ws;
    float*  feat1T  = (float*)(ws);                                   // 2 MiB
    float4* aux4    = (float4*)(ws + (2u << 20));                     // 128 KiB
    float4* flow4   = (float4*)(ws + (2u << 20) + (128u << 10));      // 128 KiB
    int*    knn_idx = (int*)  (ws + (2u << 20) + (256u << 10));       // 1 MiB
    float*  partd   = (float*)(ws + (3u << 20) + (256u << 10));      // 4 MiB
    int*    parti   = (int*)  (ws + (7u << 20) + (256u << 10));      // 4 MiB

    hipLaunchKernelGGL(k_pack, dim3(N1 / 64, NB), dim3(256), 0, stream,
                       xyz1, feat1, flow, feat1T, aux4, flow4);
    hipLaunchKernelGGL(k_knn3, dim3(NB * N2 / 256, SPLIT), dim3(256), 0, stream,
                       xyz1, xyz2, partd, parti);
    hipLaunchKernelGGL(k_merge2, dim3(NB * N2 / 256), dim3(256), 0, stream,
                       partd, parti, knn_idx);
    hipLaunchKernelGGL(k_mlp, dim3(NB * N2 / 32), dim3(256), 0, stream,
                       feat1T, aux4, flow4, knn_idx, xyz2, W1, b1, W2, b2, out);
}

// Round 6
// 353.943 us; speedup vs baseline: 1.1858x; 1.1858x over previous
//
#include <hip/hip_runtime.h>
#include <cstdint>
#include <cstddef>

#define NB    2
#define N1    4096
#define N2    16384
#define CF    64
#define KNN   8
#define SPLIT 8
#define NS    (N1 / SPLIT)   // 512 candidates per split

// ---------------------------------------------------------------------------
// Scalarized stable top-8 insert (merge kernel): strict <, descending update
// order reading pre-update values -> lower index wins ties (= top_k).
// ---------------------------------------------------------------------------
#define TKDECL(P) \
    float P##d0=INFINITY,P##d1=INFINITY,P##d2=INFINITY,P##d3=INFINITY, \
          P##d4=INFINITY,P##d5=INFINITY,P##d6=INFINITY,P##d7=INFINITY; \
    int   P##i0=0,P##i1=0,P##i2=0,P##i3=0,P##i4=0,P##i5=0,P##i6=0,P##i7=0

#define TKINS(P, dv, ix) do { \
    const bool c0_ = (dv) < P##d0, c1_ = (dv) < P##d1, c2_ = (dv) < P##d2, c3_ = (dv) < P##d3; \
    const bool c4_ = (dv) < P##d4, c5_ = (dv) < P##d5, c6_ = (dv) < P##d6, c7_ = (dv) < P##d7; \
    P##d7 = c6_ ? P##d6 : (c7_ ? (dv) : P##d7);  P##i7 = c6_ ? P##i6 : (c7_ ? (ix) : P##i7); \
    P##d6 = c5_ ? P##d5 : (c6_ ? (dv) : P##d6);  P##i6 = c5_ ? P##i5 : (c6_ ? (ix) : P##i6); \
    P##d5 = c4_ ? P##d4 : (c5_ ? (dv) : P##d5);  P##i5 = c4_ ? P##i4 : (c5_ ? (ix) : P##i5); \
    P##d4 = c3_ ? P##d3 : (c4_ ? (dv) : P##d4);  P##i4 = c3_ ? P##i3 : (c4_ ? (ix) : P##i4); \
    P##d3 = c2_ ? P##d2 : (c3_ ? (dv) : P##d3);  P##i3 = c2_ ? P##i2 : (c3_ ? (ix) : P##i3); \
    P##d2 = c1_ ? P##d1 : (c2_ ? (dv) : P##d2);  P##i2 = c1_ ? P##i1 : (c2_ ? (ix) : P##i2); \
    P##d1 = c0_ ? P##d0 : (c1_ ? (dv) : P##d1);  P##i1 = c0_ ? P##i0 : (c1_ ? (ix) : P##i1); \
    P##d0 = c0_ ? (dv) : P##d0;                  P##i0 = c0_ ? (ix) : P##i0; \
} while (0)

// ---------------------------------------------------------------------------
// kernel 0: transpose feat1 [B,C,N1] -> feat1T [B,N1,C]; pack xyz1/flow float4
// ---------------------------------------------------------------------------
__global__ __launch_bounds__(256, 2) void k_pack(
    const float* __restrict__ xyz1, const float* __restrict__ feat1,
    const float* __restrict__ flow,
    float* __restrict__ feat1T, float4* __restrict__ aux4,
    float4* __restrict__ flow4)
{
    __shared__ float tile[64][65];
    const int b  = blockIdx.y;
    const int n0 = blockIdx.x * 64;
    const int tid = threadIdx.x;
    const int nl = tid & 63, cq = tid >> 6;

#pragma unroll
    for (int r = 0; r < 16; ++r) {
        const int c = r * 4 + cq;
        tile[c][nl] = feat1[((size_t)(b * CF + c)) * N1 + n0 + nl];
    }
    __syncthreads();
#pragma unroll
    for (int r = 0; r < 16; ++r) {
        const int nn = r * 4 + cq;
        feat1T[((size_t)(b * N1 + n0 + nn)) * CF + nl] = tile[nl][nn];
    }
    if (tid < 64) {
        const int n = n0 + tid;
        const float x = xyz1[(b * 3 + 0) * N1 + n];
        const float y = xyz1[(b * 3 + 1) * N1 + n];
        const float z = xyz1[(b * 3 + 2) * N1 + n];
        aux4[b * N1 + n] = make_float4(x, y, z, 0.f);
        const float fx = flow[(b * 3 + 0) * N1 + n];
        const float fy = flow[(b * 3 + 1) * N1 + n];
        const float fz = flow[(b * 3 + 2) * N1 + n];
        flow4[b * N1 + n] = make_float4(fx, fy, fz, 0.f);
    }
}

// ---------------------------------------------------------------------------
// kernel 1: partial KNN — R4 structure (QPT=2, SPLIT=8, branchless) with the
// distance update compressed to 8 ops via v_med3_f32: for a sorted ascending
// list, new_k = med3(d, d_{k-1}, d_k) (d<=d_{k-1}: shift; between: insert;
// >=d_k: keep) and new_0 = min(d, d_0). Index updates: 8 cmp + 15 cndmask on
// the pre-update list, strict < (stable, = top_k tie semantics).
// Distance replicates reference fp32 rounding exactly:
// d = (q2 + t2) - (qt + qt), qt = ((qx*tx + qy*ty) + qz*tz), all _rn.
// ---------------------------------------------------------------------------
__global__ __launch_bounds__(256, 2) void k_knn4(
    const float* __restrict__ xyz1, const float* __restrict__ xyz2,
    float* __restrict__ partd, int* __restrict__ parti)
{
    __shared__ float4 pts[NS];  // {x, y, z, t2} — 8 KiB
    const int sp  = blockIdx.y;
    const int tid = threadIdx.x;
    const int q0  = blockIdx.x * 512 + tid;
    const int q1  = q0 + 256;
    const int b   = q0 >> 14;    // uniform per block (512 | 16384)

    for (int t = tid; t < NS; t += 256) {
        const int jg = sp * NS + t;
        const float x = xyz1[(b * 3 + 0) * N1 + jg];
        const float y = xyz1[(b * 3 + 1) * N1 + jg];
        const float z = xyz1[(b * 3 + 2) * N1 + jg];
        const float t2 = __fadd_rn(__fadd_rn(__fmul_rn(x, x), __fmul_rn(y, y)),
                                   __fmul_rn(z, z));
        pts[t] = make_float4(x, y, z, t2);
    }
    __syncthreads();

    const int n0 = q0 & (N2 - 1), n1 = n0 + 256;
    const float ax = xyz2[(b * 3 + 0) * N2 + n0];
    const float ay = xyz2[(b * 3 + 1) * N2 + n0];
    const float az = xyz2[(b * 3 + 2) * N2 + n0];
    const float a2 = __fadd_rn(__fadd_rn(__fmul_rn(ax, ax), __fmul_rn(ay, ay)),
                               __fmul_rn(az, az));
    const float cx = xyz2[(b * 3 + 0) * N2 + n1];
    const float cy = xyz2[(b * 3 + 1) * N2 + n1];
    const float cz = xyz2[(b * 3 + 2) * N2 + n1];
    const float c2 = __fadd_rn(__fadd_rn(__fmul_rn(cx, cx), __fmul_rn(cy, cy)),
                               __fmul_rn(cz, cz));

    float Ad0=INFINITY,Ad1=INFINITY,Ad2=INFINITY,Ad3=INFINITY,
          Ad4=INFINITY,Ad5=INFINITY,Ad6=INFINITY,Ad7=INFINITY;
    int   Ai0=0,Ai1=0,Ai2=0,Ai3=0,Ai4=0,Ai5=0,Ai6=0,Ai7=0;
    float Bd0=INFINITY,Bd1=INFINITY,Bd2=INFINITY,Bd3=INFINITY,
          Bd4=INFINITY,Bd5=INFINITY,Bd6=INFINITY,Bd7=INFINITY;
    int   Bi0=0,Bi1=0,Bi2=0,Bi3=0,Bi4=0,Bi5=0,Bi6=0,Bi7=0;

#pragma unroll 4
    for (int j = 0; j < NS; ++j) {
        const float4 p = pts[j];
        const int idx = sp * NS + j;

        const float qtA = __fadd_rn(
            __fadd_rn(__fmul_rn(ax, p.x), __fmul_rn(ay, p.y)),
            __fmul_rn(az, p.z));
        const float dA = __fsub_rn(__fadd_rn(a2, p.w), __fadd_rn(qtA, qtA));
        const float qtB = __fadd_rn(
            __fadd_rn(__fmul_rn(cx, p.x), __fmul_rn(cy, p.y)),
            __fmul_rn(cz, p.z));
        const float dB = __fsub_rn(__fadd_rn(c2, p.w), __fadd_rn(qtB, qtB));

        {   // query A: med3 distance network + cndmask index network
            const float m0 = fminf(dA, Ad0);
            const float m1 = __builtin_amdgcn_fmed3f(dA, Ad0, Ad1);
            const float m2 = __builtin_amdgcn_fmed3f(dA, Ad1, Ad2);
            const float m3 = __builtin_amdgcn_fmed3f(dA, Ad2, Ad3);
            const float m4 = __builtin_amdgcn_fmed3f(dA, Ad3, Ad4);
            const float m5 = __builtin_amdgcn_fmed3f(dA, Ad4, Ad5);
            const float m6 = __builtin_amdgcn_fmed3f(dA, Ad5, Ad6);
            const float m7 = __builtin_amdgcn_fmed3f(dA, Ad6, Ad7);
            const bool a0 = dA < Ad0, a1 = dA < Ad1, a2c = dA < Ad2, a3 = dA < Ad3;
            const bool a4 = dA < Ad4, a5 = dA < Ad5, a6 = dA < Ad6, a7 = dA < Ad7;
            Ai7 = a6 ? Ai6 : (a7 ? idx : Ai7);
            Ai6 = a5 ? Ai5 : (a6 ? idx : Ai6);
            Ai5 = a4 ? Ai4 : (a5 ? idx : Ai5);
            Ai4 = a3 ? Ai3 : (a4 ? idx : Ai4);
            Ai3 = a2c ? Ai2 : (a3 ? idx : Ai3);
            Ai2 = a1 ? Ai1 : (a2c ? idx : Ai2);
            Ai1 = a0 ? Ai0 : (a1 ? idx : Ai1);
            Ai0 = a0 ? idx : Ai0;
            Ad0=m0; Ad1=m1; Ad2=m2; Ad3=m3; Ad4=m4; Ad5=m5; Ad6=m6; Ad7=m7;
        }
        {   // query B
            const float m0 = fminf(dB, Bd0);
            const float m1 = __builtin_amdgcn_fmed3f(dB, Bd0, Bd1);
            const float m2 = __builtin_amdgcn_fmed3f(dB, Bd1, Bd2);
            const float m3 = __builtin_amdgcn_fmed3f(dB, Bd2, Bd3);
            const float m4 = __builtin_amdgcn_fmed3f(dB, Bd3, Bd4);
            const float m5 = __builtin_amdgcn_fmed3f(dB, Bd4, Bd5);
            const float m6 = __builtin_amdgcn_fmed3f(dB, Bd5, Bd6);
            const float m7 = __builtin_amdgcn_fmed3f(dB, Bd6, Bd7);
            const bool a0 = dB < Bd0, a1 = dB < Bd1, a2c = dB < Bd2, a3 = dB < Bd3;
            const bool a4 = dB < Bd4, a5 = dB < Bd5, a6 = dB < Bd6, a7 = dB < Bd7;
            Bi7 = a6 ? Bi6 : (a7 ? idx : Bi7);
            Bi6 = a5 ? Bi5 : (a6 ? idx : Bi6);
            Bi5 = a4 ? Bi4 : (a5 ? idx : Bi5);
            Bi4 = a3 ? Bi3 : (a4 ? idx : Bi4);
            Bi3 = a2c ? Bi2 : (a3 ? idx : Bi3);
            Bi2 = a1 ? Bi1 : (a2c ? idx : Bi2);
            Bi1 = a0 ? Bi0 : (a1 ? idx : Bi1);
            Bi0 = a0 ? idx : Bi0;
            Bd0=m0; Bd1=m1; Bd2=m2; Bd3=m3; Bd4=m4; Bd5=m5; Bd6=m6; Bd7=m7;
        }
    }

    {
        float* pd = partd + ((size_t)q0 * SPLIT + sp) * KNN;
        int*   pi = parti + ((size_t)q0 * SPLIT + sp) * KNN;
        pd[0]=Ad0; pd[1]=Ad1; pd[2]=Ad2; pd[3]=Ad3; pd[4]=Ad4; pd[5]=Ad5; pd[6]=Ad6; pd[7]=Ad7;
        pi[0]=Ai0; pi[1]=Ai1; pi[2]=Ai2; pi[3]=Ai3; pi[4]=Ai4; pi[5]=Ai5; pi[6]=Ai6; pi[7]=Ai7;
    }
    {
        float* pd = partd + ((size_t)q1 * SPLIT + sp) * KNN;
        int*   pi = parti + ((size_t)q1 * SPLIT + sp) * KNN;
        pd[0]=Bd0; pd[1]=Bd1; pd[2]=Bd2; pd[3]=Bd3; pd[4]=Bd4; pd[5]=Bd5; pd[6]=Bd6; pd[7]=Bd7;
        pi[0]=Bi0; pi[1]=Bi1; pi[2]=Bi2; pi[3]=Bi3; pi[4]=Bi4; pi[5]=Bi5; pi[6]=Bi6; pi[7]=Bi7;
    }
}

// ---------------------------------------------------------------------------
// kernel 2: merge SPLIT partial top-8 lists (ascending split order -> stable)
// ---------------------------------------------------------------------------
__global__ __launch_bounds__(256, 2) void k_merge2(
    const float* __restrict__ partd, const int* __restrict__ parti,
    int* __restrict__ knn_idx)
{
    const int q = blockIdx.x * 256 + threadIdx.x;
    const float* pd = partd + (size_t)q * SPLIT * KNN;
    const int*   pi = parti + (size_t)q * SPLIT * KNN;

    TKDECL(M);
#pragma unroll
    for (int t = 0; t < SPLIT * KNN; ++t) {
        const float d = pd[t];
        const int   i = pi[t];
        TKINS(M, d, i);
    }
    int* ko = knn_idx + (size_t)q * KNN;
    ko[0]=Mi0; ko[1]=Mi1; ko[2]=Mi2; ko[3]=Mi3; ko[4]=Mi4; ko[5]=Mi5; ko[6]=Mi6; ko[7]=Mi7;
}

// ---------------------------------------------------------------------------
// kernel 3: gather + MLP + softmax + weighted flow sum — SINGLE-WAVE blocks
// (64 threads, 4 queries/wave): __syncthreads degenerates to a cheap waitcnt
// (no cross-wave skew), and all gathers are software-pipelined one iteration
// ahead so the global-load latency hides under the ~2000-cycle compute.
// Math path identical to R5 (same DOT17 / butterfly / SMAX8 order).
// ---------------------------------------------------------------------------
#define ACC4(h, wv, iv) \
    h = fmaf((wv).x, (iv).x, h); h = fmaf((wv).y, (iv).y, h); \
    h = fmaf((wv).z, (iv).z, h); h = fmaf((wv).w, (iv).w, h)

#define DOT17(h, ivr) do { \
    ACC4(h, w0,  (ivr)[0]);  ACC4(h, w1,  (ivr)[1]);  ACC4(h, w2,  (ivr)[2]); \
    ACC4(h, w3,  (ivr)[3]);  ACC4(h, w4,  (ivr)[4]);  ACC4(h, w5,  (ivr)[5]); \
    ACC4(h, w6,  (ivr)[6]);  ACC4(h, w7,  (ivr)[7]);  ACC4(h, w8,  (ivr)[8]); \
    ACC4(h, w9,  (ivr)[9]);  ACC4(h, w10, (ivr)[10]); ACC4(h, w11, (ivr)[11]); \
    ACC4(h, w12, (ivr)[12]); ACC4(h, w13, (ivr)[13]); ACC4(h, w14, (ivr)[14]); \
    ACC4(h, w15, (ivr)[15]); ACC4(h, w16, (ivr)[16]); \
} while (0)

#define BFLY(p) \
    p += __shfl_xor(p, 32, 64); p += __shfl_xor(p, 16, 64); \
    p += __shfl_xor(p,  8, 64); p += __shfl_xor(p,  4, 64); \
    p += __shfl_xor(p,  2, 64); p += __shfl_xor(p,  1, 64)

#define L2RED(hk, a0, a1, a2) do { \
    float hv_ = (hk); hv_ = hv_ >= 0.f ? hv_ : 0.1f * hv_; \
    float p0_ = w2a * hv_, p1_ = w2b * hv_, p2_ = w2c * hv_; \
    BFLY(p0_); BFLY(p1_); BFLY(p2_); \
    a0 = p0_ + b20; a1 = p1_ + b21; a2 = p2_ + b22; \
} while (0)

#define SMAX8(sa, sb, sc, sd, se, sf, sg, sh, CH, res) do { \
    const float m_ = fmaxf(fmaxf(fmaxf(sa, sb), fmaxf(sc, sd)), \
                           fmaxf(fmaxf(se, sf), fmaxf(sg, sh))); \
    const float e0_ = __expf(sa - m_), e1_ = __expf(sb - m_); \
    const float e2_ = __expf(sc - m_), e3_ = __expf(sd - m_); \
    const float e4_ = __expf(se - m_), e5_ = __expf(sf - m_); \
    const float e6_ = __expf(sg - m_), e7_ = __expf(sh - m_); \
    const float S_ = ((e0_ + e1_) + (e2_ + e3_)) + ((e4_ + e5_) + (e6_ + e7_)); \
    float acc_ = e0_ * flf[0 * 4 + CH]; \
    acc_ = fmaf(e1_, flf[1 * 4 + CH], acc_); acc_ = fmaf(e2_, flf[2 * 4 + CH], acc_); \
    acc_ = fmaf(e3_, flf[3 * 4 + CH], acc_); acc_ = fmaf(e4_, flf[4 * 4 + CH], acc_); \
    acc_ = fmaf(e5_, flf[5 * 4 + CH], acc_); acc_ = fmaf(e6_, flf[6 * 4 + CH], acc_); \
    acc_ = fmaf(e7_, flf[7 * 4 + CH], acc_); \
    res = acc_ / S_; \
} while (0)

#define MLP_STEP(IT, IDNEXT) do { \
    const int n_ = n0 + (IT); \
    float4* drow = (float4*)&inbuf[k][0]; \
    drow[p * 2] = g0; drow[p * 2 + 1] = g1; \
    if (p == 0) { \
        inbuf[k][64] = axv.x - qx; inbuf[k][65] = axv.y - qy; \
        inbuf[k][66] = axv.z - qz; inbuf[k][67] = 0.f; \
    } \
    if (p == 1) flbuf[k] = flv; \
    __syncthreads(); \
    if ((IT) < 3) {   /* prefetch next query's gather under this compute */ \
        const float4* fr_ = (const float4*)(feat1T + (size_t)(base + (IDNEXT)) * CF); \
        g0 = fr_[p * 2]; g1 = fr_[p * 2 + 1]; \
        axv = aux4[base + (IDNEXT)]; flv = flow4[base + (IDNEXT)]; \
        qx = xyz2[(b * 3 + 0) * N2 + n_ + 1]; \
        qy = xyz2[(b * 3 + 1) * N2 + n_ + 1]; \
        qz = xyz2[(b * 3 + 2) * N2 + n_ + 1]; \
    } \
    float h0 = b1v, h1 = b1v, h2 = b1v, h3 = b1v; \
    float h4 = b1v, h5 = b1v, h6 = b1v, h7 = b1v; \
    DOT17(h0, ((const float4*)&inbuf[0][0])); \
    DOT17(h1, ((const float4*)&inbuf[1][0])); \
    DOT17(h2, ((const float4*)&inbuf[2][0])); \
    DOT17(h3, ((const float4*)&inbuf[3][0])); \
    DOT17(h4, ((const float4*)&inbuf[4][0])); \
    DOT17(h5, ((const float4*)&inbuf[5][0])); \
    DOT17(h6, ((const float4*)&inbuf[6][0])); \
    DOT17(h7, ((const float4*)&inbuf[7][0])); \
    float s00, s01, s02, s03, s04, s05, s06, s07; \
    float s10, s11, s12, s13, s14, s15, s16, s17; \
    float s20, s21, s22, s23, s24, s25, s26, s27; \
    L2RED(h0, s00, s10, s20); L2RED(h1, s01, s11, s21); \
    L2RED(h2, s02, s12, s22); L2RED(h3, s03, s13, s23); \
    L2RED(h4, s04, s14, s24); L2RED(h5, s05, s15, s25); \
    L2RED(h6, s06, s16, s26); L2RED(h7, s07, s17, s27); \
    float res0, res1, res2; \
    SMAX8(s00, s01, s02, s03, s04, s05, s06, s07, 0, res0); \
    SMAX8(s10, s11, s12, s13, s14, s15, s16, s17, 1, res1); \
    SMAX8(s20, s21, s22, s23, s24, s25, s26, s27, 2, res2); \
    const float resv = lane == 0 ? res0 : (lane == 1 ? res1 : res2); \
    if (lane < 3) out[((size_t)(b * 3 + lane)) * N2 + n_] = resv; \
} while (0)

__global__ __launch_bounds__(64, 2) void k_mlp2(
    const float* __restrict__ feat1T, const float4* __restrict__ aux4,
    const float4* __restrict__ flow4, const int* __restrict__ knn_idx,
    const float* __restrict__ xyz2,
    const float* __restrict__ W1, const float* __restrict__ b1,
    const float* __restrict__ W2, const float* __restrict__ b2,
    float* __restrict__ out)
{
    __shared__ __align__(16) float w1s[64 * 68];   // 17.0 KiB
    __shared__ __align__(16) float inbuf[8][68];   //  2.1 KiB
    __shared__ __align__(16) float4 flbuf[8];

    const int lane = threadIdx.x;   // single wave
    for (int t = lane; t < 64 * 67; t += 64) {
        const int o = t / 67, c = t - o * 67;
        w1s[o * 68 + c] = W1[t];
    }
    w1s[lane * 68 + 67] = 0.f;

    const float b1v = b1[lane];
    const float w2a = W2[lane], w2b = W2[64 + lane], w2c = W2[128 + lane];
    const float b20 = b2[0], b21 = b2[1], b22 = b2[2];
    __syncthreads();

    const float4* wr = (const float4*)&w1s[lane * 68];
    const float4 w0 = wr[0],  w1 = wr[1],  w2 = wr[2],  w3 = wr[3];
    const float4 w4 = wr[4],  w5 = wr[5],  w6 = wr[6],  w7 = wr[7];
    const float4 w8 = wr[8],  w9 = wr[9],  w10 = wr[10], w11 = wr[11];
    const float4 w12 = wr[12], w13 = wr[13], w14 = wr[14], w15 = wr[15];
    const float4 w16 = wr[16];

    const int k = lane >> 3, p = lane & 7;
    const float* flf = (const float*)&flbuf[0];

    const int q0   = blockIdx.x * 4;          // 4 queries per wave
    const int b    = q0 >> 14;                // 4 | 16384 -> uniform
    const int base = b * N1;
    const int n0   = q0 & (N2 - 1);

    // neighbor ids for all 4 queries (per-lane k), issued up front
    const int id0 = knn_idx[(size_t)(q0 + 0) * KNN + k];
    const int id1 = knn_idx[(size_t)(q0 + 1) * KNN + k];
    const int id2 = knn_idx[(size_t)(q0 + 2) * KNN + k];
    const int id3 = knn_idx[(size_t)(q0 + 3) * KNN + k];

    // stage for iteration 0
    const float4* fr0 = (const float4*)(feat1T + (size_t)(base + id0) * CF);
    float4 g0 = fr0[p * 2], g1 = fr0[p * 2 + 1];
    float4 axv = aux4[base + id0];
    float4 flv = flow4[base + id0];
    float qx = xyz2[(b * 3 + 0) * N2 + n0];
    float qy = xyz2[(b * 3 + 1) * N2 + n0];
    float qz = xyz2[(b * 3 + 2) * N2 + n0];

    MLP_STEP(0, id1);
    MLP_STEP(1, id2);
    MLP_STEP(2, id3);
    MLP_STEP(3, id3);
}

// ---------------------------------------------------------------------------
extern "C" void kernel_launch(void* const* d_in, const int* in_sizes, int n_in,
                              void* d_out, int out_size, void* d_ws, size_t ws_size,
                              hipStream_t stream)
{
    const float* xyz1  = (const float*)d_in[0];
    const float* xyz2  = (const float*)d_in[1];
    const float* feat1 = (const float*)d_in[2];
    const float* flow  = (const float*)d_in[3];
    const float* W1    = (const float*)d_in[4];
    const float* b1    = (const float*)d_in[5];
    const float* W2    = (const float*)d_in[6];
    const float* b2    = (const float*)d_in[7];
    float* out = (float*)d_out;

    char* ws = (char*)d_ws;
    float*  feat1T  = (float*)(ws);                                   // 2 MiB
    float4* aux4    = (float4*)(ws + (2u << 20));                     // 128 KiB
    float4* flow4   = (float4*)(ws + (2u << 20) + (128u << 10));      // 128 KiB
    int*    knn_idx = (int*)  (ws + (2u << 20) + (256u << 10));       // 1 MiB
    float*  partd   = (float*)(ws + (3u << 20) + (256u << 10));       // 8 MiB
    int*    parti   = (int*)  (ws + (11u << 20) + (256u << 10));      // 8 MiB

    hipLaunchKernelGGL(k_pack, dim3(N1 / 64, NB), dim3(256), 0, stream,
                       xyz1, feat1, flow, feat1T, aux4, flow4);
    hipLaunchKernelGGL(k_knn4, dim3(NB * N2 / 512, SPLIT), dim3(256), 0, stream,
                       xyz1, xyz2, partd, parti);
    hipLaunchKernelGGL(k_merge2, dim3(NB * N2 / 256), dim3(256), 0, stream,
                       partd, parti, knn_idx);
    hipLaunchKernelGGL(k_mlp2, dim3(NB * N2 / 4), dim3(64), 0, stream,
                       feat1T, aux4, flow4, knn_idx, xyz2, W1, b1, W2, b2, out);
}